// Round 7
// baseline (476.057 us; speedup 1.0000x reference)
//
#include <hip/hip_runtime.h>
#include <stdint.h>

#define NROWS 16384
#define KDIM  512
#define BM 256
#define BN 256
#define CT 2
#define NCHUNK 32           // 16384 / (BN*CT)
#define INV_T 14.285714285714286f
#define LOG2E 1.4426950408889634f
#define LN2   0.6931471805599453f

typedef __bf16 bf16x8 __attribute__((ext_vector_type(8)));
typedef float  f32x4  __attribute__((ext_vector_type(4)));
typedef unsigned short u16x8 __attribute__((ext_vector_type(8)));

// async global->LDS, 16B/lane; LDS dest = wave-uniform base + lane*16
__device__ __forceinline__ void gload_lds16(const void* gptr, void* lptr) {
    uint32_t loff = (uint32_t)(uintptr_t)lptr;
    loff = __builtin_amdgcn_readfirstlane(loff);
    __builtin_amdgcn_global_load_lds(
        (const uint32_t __attribute__((address_space(1)))*)(uintptr_t)gptr,
        (uint32_t __attribute__((address_space(3)))*)(uintptr_t)loff,
        16, 0, 0);
}

// Fragment-major panel for mfma_16x16x32_bf16:
// granule(row r, octet ko=k/8) at idx = (kt*64 + rb)*2048 + (mf*2+ksub)*64 + oo*16 + r16
//   kt=ko>>3, ksub=(ko>>2)&1, oo=ko&3, rb=r>>8, mf=(r>>4)&15, r16=r&15.
// One K-tile x 256-row chunk = 2048 granules = 32KB contiguous.
// MFMA lane l (row=l&15, octet=l>>4) reads granule base+l: lane-contiguous, conflict-free.

// ---- kernel 1: L2 normalize + scale + bf16 cast into fragment-major panel ----
__global__ void k_norm(const float* __restrict__ X, char* __restrict__ Y, float scale) {
    const int row  = blockIdx.x * 4 + (threadIdx.x >> 6);
    const int lane = threadIdx.x & 63;      // lane = k-octet ko
    const float* xr = X + (size_t)row * KDIM + lane * 8;
    float4 a = *(const float4*)xr;
    float4 b = *(const float4*)(xr + 4);
    float ss = a.x*a.x + a.y*a.y + a.z*a.z + a.w*a.w
             + b.x*b.x + b.y*b.y + b.z*b.z + b.w*b.w;
    #pragma unroll
    for (int off = 1; off < 64; off <<= 1) ss += __shfl_xor(ss, off);
    const float s = scale / fmaxf(sqrtf(ss), 1e-12f);
    __bf16 o[8];
    o[0] = (__bf16)(a.x * s); o[1] = (__bf16)(a.y * s);
    o[2] = (__bf16)(a.z * s); o[3] = (__bf16)(a.w * s);
    o[4] = (__bf16)(b.x * s); o[5] = (__bf16)(b.y * s);
    o[6] = (__bf16)(b.z * s); o[7] = (__bf16)(b.w * s);
    const int kt = lane >> 3, ksub = (lane >> 2) & 1, oo = lane & 3;
    const size_t gr = ((size_t)(kt * 64 + (row >> 8)) * 2048)
                    + ((((row >> 4) & 15) * 2 + ksub) * 64) + oo * 16 + (row & 15);
    *(u16x8*)(Y + gr * 16) = *(const u16x8*)o;
}

// ---- kernel 2: fused GEMM + exp2 + row-sum. 256x256 tile, 8 waves (2Mx4N),
// 16x16x32 MFMA, 8-phase quadrant schedule, double-buffered 64KB K-tile bufs.
__global__ __launch_bounds__(512, 2) void k_gemm(const char* __restrict__ A,
                                                 const char* __restrict__ B,
                                                 float* __restrict__ S_part) {
    __shared__ __align__(16) char L[2 * 65536];   // buf{0,1}: A 32KB + B 32KB
    __shared__ float rowsum[4][BM];
    char* Lc = (char*)L;

    const int tid  = threadIdx.x;
    const int lane = tid & 63;
    const int w    = tid >> 6;           // 0..7
    const int wr   = w >> 2, wc = w & 3; // 2M x 4N wave grid; wave tile 128x64
    // XCD supertile swizzle: per XCD 8 supertiles of (8 brow x 4 chunk)
    const int bid  = blockIdx.x;
    const int xcd  = bid & 7;
    const int idx  = bid >> 3;
    const int st   = idx >> 5;
    const int wsub = idx & 31;
    const int brow  = (st * 8 + (wsub >> 2)) * BM;
    const int chunk = xcd * 4 + (wsub & 3);   // 0..31
    const int rbA = brow >> 8;

// stage one 32KB (kt, rowblk) chunk linearly: 4 x 8KB, per call tid*16 (lane-exact)
#define STG(P_, RB_, KT_, LB_) do {                                           \
        const char* g_ = (P_) + ((size_t)((KT_) * 64 + (RB_)) * 32768) + tid * 16; \
        char* l_ = Lc + (LB_) + tid * 16;                                     \
        gload_lds16(g_,         l_);                                          \
        gload_lds16(g_ +  8192, l_ +  8192);                                  \
        gload_lds16(g_ + 16384, l_ + 16384);                                  \
        gload_lds16(g_ + 24576, l_ + 24576);                                  \
    } while (0)

#define RD_A4(MLO_, BUFB_) do {                                               \
        _Pragma("unroll") for (int m_ = 0; m_ < 4; ++m_)                      \
        _Pragma("unroll") for (int ks_ = 0; ks_ < 2; ++ks_)                   \
            a[m_][ks_] = *(const bf16x8*)(Lc + (BUFB_)                        \
                + (((wr * 8 + (MLO_) + m_) * 2 + ks_) << 10) + (lane << 4));  \
    } while (0)

#define RD_B2(NLO_, BUFB_) do {                                               \
        _Pragma("unroll") for (int n_ = 0; n_ < 2; ++n_)                      \
        _Pragma("unroll") for (int ks_ = 0; ks_ < 2; ++ks_)                   \
            b[n_][ks_] = *(const bf16x8*)(Lc + (BUFB_) + 32768                \
                + (((wc * 4 + (NLO_) + n_) * 2 + ks_) << 10) + (lane << 4));  \
    } while (0)

#define MM8(MLO_, NLO_) do {                                                  \
        __builtin_amdgcn_s_setprio(1);                                        \
        _Pragma("unroll") for (int m_ = 0; m_ < 4; ++m_)                      \
        _Pragma("unroll") for (int n_ = 0; n_ < 2; ++n_)                      \
        _Pragma("unroll") for (int ks_ = 0; ks_ < 2; ++ks_)                   \
            acc[(MLO_) + m_][(NLO_) + n_] =                                   \
                __builtin_amdgcn_mfma_f32_16x16x32_bf16(                      \
                    a[m_][ks_], b[n_][ks_], acc[(MLO_) + m_][(NLO_) + n_],    \
                    0, 0, 0);                                                 \
        __builtin_amdgcn_s_setprio(0);                                        \
    } while (0)

#define BAR_LGKM() do {                                                       \
        __builtin_amdgcn_s_barrier();                                         \
        asm volatile("s_waitcnt lgkmcnt(0)" ::: "memory");                    \
        __builtin_amdgcn_sched_barrier(0);                                    \
    } while (0)

    float rowacc = 0.f;
    for (int ct = 0; ct < CT; ++ct) {
        const int rbB = chunk * CT + ct;     // B panel rowblk (cols/256)
        f32x4 acc[8][4] = {};
        bf16x8 a[4][2], b[2][2];

        // prologue: stage kt0 -> buf0, kt1 -> buf1 (8 loads each); wait kt0
        STG(A, rbA, 0, 0);
        STG(B, rbB, 0, 32768);
        STG(A, rbA, 1, 65536);
        STG(B, rbB, 1, 98304);
        asm volatile("s_waitcnt vmcnt(8)" ::: "memory");
        __builtin_amdgcn_s_barrier();

        #pragma unroll
        for (int i = 0; i < 4; ++i) {
            // ---- K-tile 2i (buf0) ----
            // ph1: quadrant (m0-3 x n0-1); stage buf1's next A (kt 2i+1, i>0)
            RD_A4(0, 0); RD_B2(0, 0);
            if (i > 0) STG(A, rbA, 2 * i + 1, 65536);
            asm volatile("s_waitcnt lgkmcnt(8)" ::: "memory");
            BAR_LGKM(); MM8(0, 0); __builtin_amdgcn_s_barrier();
            // ph2: (m0-3 x n2-3); stage buf1's next B
            RD_B2(2, 0);
            if (i > 0) STG(B, rbB, 2 * i + 1, 98304);
            BAR_LGKM(); MM8(0, 2); __builtin_amdgcn_s_barrier();
            // ph3: (m4-7 x n2-3)
            RD_A4(4, 0);
            BAR_LGKM(); MM8(4, 2); __builtin_amdgcn_s_barrier();
            // ph4: (m4-7 x n0-1); buf1 content (kt 2i+1) must be landed
            RD_B2(0, 0);
            asm volatile("s_waitcnt vmcnt(0)" ::: "memory");
            BAR_LGKM(); MM8(4, 0); __builtin_amdgcn_s_barrier();
            // ---- K-tile 2i+1 (buf1) ----
            // ph5: stage buf0's next A (kt 2i+2, i<3)
            RD_A4(0, 65536); RD_B2(0, 65536);
            if (i < 3) STG(A, rbA, 2 * i + 2, 0);
            asm volatile("s_waitcnt lgkmcnt(8)" ::: "memory");
            BAR_LGKM(); MM8(0, 0); __builtin_amdgcn_s_barrier();
            // ph6: stage buf0's next B
            RD_B2(2, 65536);
            if (i < 3) STG(B, rbB, 2 * i + 2, 32768);
            BAR_LGKM(); MM8(0, 2); __builtin_amdgcn_s_barrier();
            // ph7
            RD_A4(4, 65536);
            BAR_LGKM(); MM8(4, 2); __builtin_amdgcn_s_barrier();
            // ph8: buf0 content (kt 2i+2) must be landed before next iter ph1
            RD_B2(0, 65536);
            if (i < 3) asm volatile("s_waitcnt vmcnt(0)" ::: "memory");
            BAR_LGKM(); MM8(4, 0); __builtin_amdgcn_s_barrier();
        }

        // epilogue: exp2 + row-reduce. C/D: row=(lane>>4)*4+r, col=lane&15
        #pragma unroll
        for (int m = 0; m < 8; ++m) {
            float rs[4];
            #pragma unroll
            for (int r = 0; r < 4; ++r)
                rs[r] = __builtin_amdgcn_exp2f(acc[m][0][r])
                      + __builtin_amdgcn_exp2f(acc[m][1][r])
                      + __builtin_amdgcn_exp2f(acc[m][2][r])
                      + __builtin_amdgcn_exp2f(acc[m][3][r]);
            #pragma unroll
            for (int off = 8; off >= 1; off >>= 1)
                #pragma unroll
                for (int r = 0; r < 4; ++r)
                    rs[r] += __shfl_xor(rs[r], off);
            if ((lane & 15) == 0) {
                #pragma unroll
                for (int r = 0; r < 4; ++r)
                    rowsum[wc][wr * 128 + m * 16 + (lane >> 4) * 4 + r] = rs[r];
            }
        }
        __syncthreads();
        if (tid < BM)
            rowacc += rowsum[0][tid] + rowsum[1][tid] + rowsum[2][tid] + rowsum[3][tid];
        __syncthreads();
    }
#undef STG
#undef RD_A4
#undef RD_B2
#undef MM8
#undef BAR_LGKM
    if (tid < BM) S_part[(size_t)chunk * NROWS + brow + tid] = rowacc;
}

// ---- kernel 3: diagonal logits (log2-scaled), fragment-major panel ----
__global__ void k_diag(const char* __restrict__ A, const char* __restrict__ B,
                       float* __restrict__ diag) {
    const int row  = blockIdx.x * 4 + (threadIdx.x >> 6);
    const int lane = threadIdx.x & 63;
    const int kt = lane >> 3, ksub = (lane >> 2) & 1, oo = lane & 3;
    const size_t gr = ((size_t)(kt * 64 + (row >> 8)) * 2048)
                    + ((((row >> 4) & 15) * 2 + ksub) * 64) + oo * 16 + (row & 15);
    const bf16x8 va = *(const bf16x8*)(A + gr * 16);
    const bf16x8 vb = *(const bf16x8*)(B + gr * 16);
    float d = 0.f;
    #pragma unroll
    for (int i = 0; i < 8; ++i) d += (float)va[i] * (float)vb[i];
    #pragma unroll
    for (int off2 = 1; off2 < 64; off2 <<= 1) d += __shfl_xor(d, off2);
    if (lane == 0) diag[row] = d;
}

// ---- kernel 4: per-row loss + deterministic block partials ----
__global__ void k_loss(const float* __restrict__ S_part, const float* __restrict__ diag,
                       float* __restrict__ partial) {
    const int g = blockIdx.x * 256 + threadIdx.x;
    float S = 0.f;
    #pragma unroll
    for (int c = 0; c < NCHUNK; ++c) S += S_part[(size_t)c * NROWS + g];
    float v = logf(S) - diag[g] * LN2;   // diag is log2-scaled
    __shared__ float wsum[4];
    #pragma unroll
    for (int off = 1; off < 64; off <<= 1) v += __shfl_xor(v, off);
    if ((threadIdx.x & 63) == 0) wsum[threadIdx.x >> 6] = v;
    __syncthreads();
    if (threadIdx.x == 0) partial[blockIdx.x] = wsum[0] + wsum[1] + wsum[2] + wsum[3];
}

__global__ void k_final(const float* __restrict__ partial, float* __restrict__ out) {
    float v = partial[threadIdx.x];
    #pragma unroll
    for (int off = 1; off < 64; off <<= 1) v += __shfl_xor(v, off);
    if (threadIdx.x == 0) out[0] = v * (1.0f / (float)NROWS);
}

extern "C" void kernel_launch(void* const* d_in, const int* in_sizes, int n_in,
                              void* d_out, int out_size, void* d_ws, size_t ws_size,
                              hipStream_t stream) {
    const float* f1 = (const float*)d_in[0];
    const float* f2 = (const float*)d_in[1];
    float* out = (float*)d_out;

    char* ws = (char*)d_ws;
    char*  f1p   = ws;                                  // 16 MB panel
    char*  f2p   = ws + (16u << 20);                    // 16 MB panel
    float* S_part = (float*)(ws + (32u << 20));         // 2 MB [NCHUNK][NROWS]
    float* diag   = (float*)(ws + (34u << 20));         // 64 KB
    float* part   = (float*)(ws + (34u << 20) + (1u << 16)); // 256 B

    k_norm<<<dim3(NROWS / 4), dim3(256), 0, stream>>>(f1, f1p, INV_T * LOG2E);
    k_norm<<<dim3(NROWS / 4), dim3(256), 0, stream>>>(f2, f2p, 1.0f);
    k_gemm<<<dim3((NROWS / BM) * NCHUNK), dim3(512), 0, stream>>>(f1p, f2p, S_part);
    k_diag<<<dim3(NROWS / 4), dim3(256), 0, stream>>>(f1p, f2p, diag);
    k_loss<<<dim3(NROWS / 256), dim3(256), 0, stream>>>(S_part, diag, part);
    k_final<<<dim3(1), dim3(64), 0, stream>>>(part, out);
}

// Round 9
// 370.483 us; speedup vs baseline: 1.2850x; 1.2850x over previous
//
#include <hip/hip_runtime.h>
#include <stdint.h>

#define NROWS 16384
#define KDIM  512
#define BM 256
#define BN 128          // per-ct column strip
#define CT 4            // strips per block -> 512-col chunk
#define NCHUNK 32       // 16384 / 512
#define NPH 16          // K-halves of 32: 512/32
#define INV_T 14.285714285714286f
#define LOG2E 1.4426950408889634f
#define LN2   0.6931471805599453f

typedef __bf16 bf16x8 __attribute__((ext_vector_type(8)));
typedef float  f32x16 __attribute__((ext_vector_type(16)));
typedef unsigned short u16x8 __attribute__((ext_vector_type(8)));

// async global->LDS, 16B/lane; LDS dest = wave-uniform base + lane*16
__device__ __forceinline__ void gload_lds16(const void* gptr, void* lptr) {
    uint32_t loff = (uint32_t)(uintptr_t)lptr;
    loff = __builtin_amdgcn_readfirstlane(loff);
    __builtin_amdgcn_global_load_lds(
        (const uint32_t __attribute__((address_space(1)))*)(uintptr_t)gptr,
        (uint32_t __attribute__((address_space(3)))*)(uintptr_t)loff,
        16, 0, 0);
}

// Fragment-major panel for mfma_32x32x16_bf16 (verified exact in R5):
// granule(row r, kh=k/32, q=(k/8)&3) at ((kh*512 + r/32)*2 + (q>>1))*64 + (q&1)*32 + (r&31)
// A wave frag read = Rgroup*2048 + ks*1024 + lane*16 : lane-contiguous, conflict-free.

// ---- kernel 1: L2 normalize + scale + bf16 cast into fragment-major panel ----
__global__ void k_norm(const float* __restrict__ X, char* __restrict__ Y, float scale) {
    const int row  = blockIdx.x * 4 + (threadIdx.x >> 6);
    const int lane = threadIdx.x & 63;
    const float* xr = X + (size_t)row * KDIM + lane * 8;
    float4 a = *(const float4*)xr;
    float4 b = *(const float4*)(xr + 4);
    float ss = a.x*a.x + a.y*a.y + a.z*a.z + a.w*a.w
             + b.x*b.x + b.y*b.y + b.z*b.z + b.w*b.w;
    #pragma unroll
    for (int off = 1; off < 64; off <<= 1) ss += __shfl_xor(ss, off);
    const float s = scale / fmaxf(sqrtf(ss), 1e-12f);
    __bf16 o[8];
    o[0] = (__bf16)(a.x * s); o[1] = (__bf16)(a.y * s);
    o[2] = (__bf16)(a.z * s); o[3] = (__bf16)(a.w * s);
    o[4] = (__bf16)(b.x * s); o[5] = (__bf16)(b.y * s);
    o[6] = (__bf16)(b.z * s); o[7] = (__bf16)(b.w * s);
    const int kh = lane >> 2, q = lane & 3;
    const size_t gr = ((size_t)(kh * 512 + (row >> 5)) * 2 + (q >> 1)) * 64
                    + ((q & 1) << 5) + (row & 31);
    *(u16x8*)(Y + gr * 16) = *(const u16x8*)o;
}

// ---- kernel 2: fused GEMM + exp2 + row-sum. 256x128 per step, 8 waves (4Mx2N),
// 32x32x16 MFMA, acc[2][2] (64 f/thread, spill-free), 4-slot 24KB LDS ring.
__global__ __launch_bounds__(512, 2) void k_gemm(const char* __restrict__ A,
                                                 const char* __restrict__ B,
                                                 float* __restrict__ S_part) {
    __shared__ __align__(16) char L[4 * 24576];   // slot: A 16KB + B 8KB
    __shared__ float rowsum[2][BM];
    char* Lc = (char*)L;

    const int tid  = threadIdx.x;
    const int lane = tid & 63;
    const int w    = tid >> 6;           // 0..7
    const int wr   = w >> 1, wc = w & 1; // 4M x 2N; wave tile 64x64
    // XCD supertile swizzle: 2048 blocks; 8 supertiles/XCD of (8 brow x 4 chunk)
    const int bid  = blockIdx.x;
    const int xcd  = bid & 7;
    const int idx  = bid >> 3;           // 0..255
    const int st   = idx >> 5;           // 0..7
    const int wsub = idx & 31;
    const int sg   = xcd * 8 + st;       // 0..63
    const int bg   = sg & 7, cg = sg >> 3;
    const int brow  = (bg * 8 + (wsub >> 2)) * BM;
    const int chunk = cg * 4 + (wsub & 3);    // 0..31, 512-col chunk
    const int rbA0 = brow >> 5;               // 8 Rgroups of A

#define STGA(KH_, S_) do {                                                    \
        const char* g_ = A + ((size_t)((KH_) * 512 + rbA0) * 2048) + tid * 16;\
        char* l_ = Lc + (S_) * 24576 + tid * 16;                              \
        gload_lds16(g_,        l_);                                           \
        gload_lds16(g_ + 8192, l_ + 8192);                                    \
    } while (0)

#define STGB(KH_, S_) do {                                                    \
        const char* g_ = B + ((size_t)((KH_) * 512 + rbB0) * 2048) + tid * 16;\
        char* l_ = Lc + (S_) * 24576 + 16384 + tid * 16;                      \
        gload_lds16(g_, l_);                                                  \
    } while (0)

    float rowacc = 0.f;
    #pragma unroll 1
    for (int ct = 0; ct < CT; ++ct) {
        const int rbB0 = (chunk * 16 + ct * 4); // 4 Rgroups of B (128 cols)
        f32x16 acc[2][2] = {};
        bf16x8 af[2][2], bf[2][2];

        // prologue: stage H0->slot0, H1->slot1; wait H0 (H1's 3 in flight)
        STGA(0, 0); STGB(0, 0);
        STGA(1, 1); STGB(1, 1);
        asm volatile("s_waitcnt vmcnt(3)" ::: "memory");
        __builtin_amdgcn_s_barrier();

        #pragma unroll
        for (int h = 0; h < NPH; ++h) {
            const char* sl = Lc + (h & 3) * 24576;
            // reads for this phase (issued before barrier; drain under it)
            #pragma unroll
            for (int m = 0; m < 2; ++m)
                #pragma unroll
                for (int ks = 0; ks < 2; ++ks)
                    af[m][ks] = *(const bf16x8*)(sl + ((wr * 2 + m) << 11)
                                                 + (ks << 10) + (lane << 4));
            #pragma unroll
            for (int n = 0; n < 2; ++n)
                #pragma unroll
                for (int ks = 0; ks < 2; ++ks)
                    bf[n][ks] = *(const bf16x8*)(sl + 16384 + ((wc * 2 + n) << 11)
                                                 + (ks << 10) + (lane << 4));
            // prefetch H(h+2)
            if (h < NPH - 2) { STGA(h + 2, (h + 2) & 3); STGB(h + 2, (h + 2) & 3); }
            __builtin_amdgcn_sched_barrier(0);
            if (h < NPH - 2)       asm volatile("s_waitcnt vmcnt(3)" ::: "memory");
            else if (h == NPH - 2) asm volatile("s_waitcnt vmcnt(0)" ::: "memory");
            __builtin_amdgcn_s_barrier();
            asm volatile("s_waitcnt lgkmcnt(0)" ::: "memory");
            __builtin_amdgcn_sched_barrier(0);
            __builtin_amdgcn_s_setprio(1);
            #pragma unroll
            for (int m = 0; m < 2; ++m)
                #pragma unroll
                for (int n = 0; n < 2; ++n)
                    #pragma unroll
                    for (int ks = 0; ks < 2; ++ks)
                        acc[m][n] = __builtin_amdgcn_mfma_f32_32x32x16_bf16(
                            af[m][ks], bf[n][ks], acc[m][n], 0, 0, 0);
            __builtin_amdgcn_s_setprio(0);
            __builtin_amdgcn_s_barrier();
        }

        // epilogue: C/D 32x32: col=lane&31, row=(r&3)+8*(r>>2)+4*(lane>>5)
        #pragma unroll
        for (int m = 0; m < 2; ++m) {
            float rs[16];
            #pragma unroll
            for (int r = 0; r < 16; ++r)
                rs[r] = __builtin_amdgcn_exp2f(acc[m][0][r])
                      + __builtin_amdgcn_exp2f(acc[m][1][r]);
            #pragma unroll
            for (int off = 16; off >= 1; off >>= 1)
                #pragma unroll
                for (int r = 0; r < 16; ++r)
                    rs[r] += __shfl_xor(rs[r], off);
            if ((lane & 31) == 0) {
                const int rb = wr * 64 + m * 32 + (lane >> 5) * 4;
                #pragma unroll
                for (int r = 0; r < 16; ++r)
                    rowsum[wc][rb + (r & 3) + 8 * (r >> 2)] = rs[r];
            }
        }
        __syncthreads();
        if (tid < BM) rowacc += rowsum[0][tid] + rowsum[1][tid];
        __syncthreads();
    }
#undef STGA
#undef STGB
    if (tid < BM) S_part[(size_t)chunk * NROWS + brow + tid] = rowacc;
}

// ---- kernel 3: diagonal logits (log2-scaled), fragment-major panel ----
__global__ void k_diag(const char* __restrict__ A, const char* __restrict__ B,
                       float* __restrict__ diag) {
    const int row  = blockIdx.x * 4 + (threadIdx.x >> 6);
    const int lane = threadIdx.x & 63;
    const int kh = lane >> 2, q = lane & 3;
    const size_t gr = ((size_t)(kh * 512 + (row >> 5)) * 2 + (q >> 1)) * 64
                    + ((q & 1) << 5) + (row & 31);
    const bf16x8 va = *(const bf16x8*)(A + gr * 16);
    const bf16x8 vb = *(const bf16x8*)(B + gr * 16);
    float d = 0.f;
    #pragma unroll
    for (int i = 0; i < 8; ++i) d += (float)va[i] * (float)vb[i];
    #pragma unroll
    for (int off2 = 1; off2 < 64; off2 <<= 1) d += __shfl_xor(d, off2);
    if (lane == 0) diag[row] = d;
}

// ---- kernel 4: per-row loss + deterministic block partials ----
__global__ void k_loss(const float* __restrict__ S_part, const float* __restrict__ diag,
                       float* __restrict__ partial) {
    const int g = blockIdx.x * 256 + threadIdx.x;
    float S = 0.f;
    #pragma unroll
    for (int c = 0; c < NCHUNK; ++c) S += S_part[(size_t)c * NROWS + g];
    float v = logf(S) - diag[g] * LN2;   // diag is log2-scaled
    __shared__ float wsum[4];
    #pragma unroll
    for (int off = 1; off < 64; off <<= 1) v += __shfl_xor(v, off);
    if ((threadIdx.x & 63) == 0) wsum[threadIdx.x >> 6] = v;
    __syncthreads();
    if (threadIdx.x == 0) partial[blockIdx.x] = wsum[0] + wsum[1] + wsum[2] + wsum[3];
}

__global__ void k_final(const float* __restrict__ partial, float* __restrict__ out) {
    float v = partial[threadIdx.x];
    #pragma unroll
    for (int off = 1; off < 64; off <<= 1) v += __shfl_xor(v, off);
    if (threadIdx.x == 0) out[0] = v * (1.0f / (float)NROWS);
}

extern "C" void kernel_launch(void* const* d_in, const int* in_sizes, int n_in,
                              void* d_out, int out_size, void* d_ws, size_t ws_size,
                              hipStream_t stream) {
    const float* f1 = (const float*)d_in[0];
    const float* f2 = (const float*)d_in[1];
    float* out = (float*)d_out;

    char* ws = (char*)d_ws;
    char*  f1p   = ws;                                  // 16 MB panel
    char*  f2p   = ws + (16u << 20);                    // 16 MB panel
    float* S_part = (float*)(ws + (32u << 20));         // 2 MB [NCHUNK][NROWS]
    float* diag   = (float*)(ws + (34u << 20));         // 64 KB
    float* part   = (float*)(ws + (34u << 20) + (1u << 16)); // 256 B

    k_norm<<<dim3(NROWS / 4), dim3(256), 0, stream>>>(f1, f1p, INV_T * LOG2E);
    k_norm<<<dim3(NROWS / 4), dim3(256), 0, stream>>>(f2, f2p, 1.0f);
    // 2048 blocks: 64 brow x 32 chunk (each block: 256 rows x 512 cols via CT=4)
    k_gemm<<<dim3((NROWS / BM) * NCHUNK), dim3(512), 0, stream>>>(f1p, f2p, S_part);
    k_diag<<<dim3(NROWS / 4), dim3(256), 0, stream>>>(f1p, f2p, diag);
    k_loss<<<dim3(NROWS / 256), dim3(256), 0, stream>>>(S_part, diag, part);
    k_final<<<dim3(1), dim3(64), 0, stream>>>(part, out);
}

// Round 10
// 358.387 us; speedup vs baseline: 1.3283x; 1.0338x over previous
//
#include <hip/hip_runtime.h>
#include <stdint.h>

#define NROWS 16384
#define KDIM  512
#define BM 256
#define BN 128          // per-ct column strip
#define CT 4            // strips per block -> 512-col chunk
#define NCHUNK 32       // 16384 / 512
#define NPH 16          // K-halves of 32: 512/32
#define INV_T 14.285714285714286f
#define LOG2E 1.4426950408889634f
#define LN2   0.6931471805599453f

typedef __bf16 bf16x8 __attribute__((ext_vector_type(8)));
typedef float  f32x16 __attribute__((ext_vector_type(16)));
typedef unsigned short u16x8 __attribute__((ext_vector_type(8)));

// async global->LDS, 16B/lane; LDS dest = wave-uniform base + lane*16
__device__ __forceinline__ void gload_lds16(const void* gptr, void* lptr) {
    uint32_t loff = (uint32_t)(uintptr_t)lptr;
    loff = __builtin_amdgcn_readfirstlane(loff);
    __builtin_amdgcn_global_load_lds(
        (const uint32_t __attribute__((address_space(1)))*)(uintptr_t)gptr,
        (uint32_t __attribute__((address_space(3)))*)(uintptr_t)loff,
        16, 0, 0);
}

// Fragment-major panel for mfma_32x32x16_bf16 (verified exact in R5/R9):
// granule(row r, kh=k/32, q=(k/8)&3) at ((kh*512 + r/32)*2 + (q>>1))*64 + (q&1)*32 + (r&31)
// A wave frag read = Rgroup*2048 + ks*1024 + lane*16 : lane-contiguous, conflict-free.

// ---- kernel 1: L2 normalize + scale + bf16 cast into fragment-major panel ----
__global__ void k_norm(const float* __restrict__ X, char* __restrict__ Y, float scale) {
    const int row  = blockIdx.x * 4 + (threadIdx.x >> 6);
    const int lane = threadIdx.x & 63;
    const float* xr = X + (size_t)row * KDIM + lane * 8;
    float4 a = *(const float4*)xr;
    float4 b = *(const float4*)(xr + 4);
    float ss = a.x*a.x + a.y*a.y + a.z*a.z + a.w*a.w
             + b.x*b.x + b.y*b.y + b.z*b.z + b.w*b.w;
    #pragma unroll
    for (int off = 1; off < 64; off <<= 1) ss += __shfl_xor(ss, off);
    const float s = scale / fmaxf(sqrtf(ss), 1e-12f);
    __bf16 o[8];
    o[0] = (__bf16)(a.x * s); o[1] = (__bf16)(a.y * s);
    o[2] = (__bf16)(a.z * s); o[3] = (__bf16)(a.w * s);
    o[4] = (__bf16)(b.x * s); o[5] = (__bf16)(b.y * s);
    o[6] = (__bf16)(b.z * s); o[7] = (__bf16)(b.w * s);
    const int kh = lane >> 2, q = lane & 3;
    const size_t gr = ((size_t)(kh * 512 + (row >> 5)) * 2 + (q >> 1)) * 64
                    + ((q & 1) << 5) + (row & 31);
    *(u16x8*)(Y + gr * 16) = *(const u16x8*)o;
}

// ---- kernel 2: fused GEMM + exp2 + row-sum. 256x128 per step, 8 waves (4Mx2N),
// 32x32x16 MFMA, double frag sets: reads(h+1) drain under MFMA(h). 4-slot ring.
__global__ __launch_bounds__(512, 1) void k_gemm(const char* __restrict__ A,
                                                 const char* __restrict__ B,
                                                 float* __restrict__ S_part) {
    __shared__ __align__(16) char L[4 * 24576];   // slot: A 16KB + B 8KB
    __shared__ float rowsum[2][BM];
    char* Lc = (char*)L;

    const int tid  = threadIdx.x;
    const int lane = tid & 63;
    const int w    = tid >> 6;           // 0..7
    const int wr   = w >> 1, wc = w & 1; // 4M x 2N; wave tile 64x64
    // XCD supertile swizzle: 2048 blocks; 8 supertiles/XCD of (8 brow x 4 chunk)
    const int bid  = blockIdx.x;
    const int xcd  = bid & 7;
    const int idx  = bid >> 3;           // 0..255
    const int st   = idx >> 5;           // 0..7
    const int wsub = idx & 31;
    const int sg   = xcd * 8 + st;       // 0..63
    const int bg   = sg & 7, cg = sg >> 3;
    const int brow  = (bg * 8 + (wsub >> 2)) * BM;
    const int chunk = cg * 4 + (wsub & 3);    // 0..31, 512-col chunk
    const int rbA0 = brow >> 5;               // 8 Rgroups of A

#define STGA(KH_, S_) do {                                                    \
        const char* g_ = A + ((size_t)((KH_) * 512 + rbA0) * 2048) + tid * 16;\
        char* l_ = Lc + (S_) * 24576 + tid * 16;                              \
        gload_lds16(g_,        l_);                                           \
        gload_lds16(g_ + 8192, l_ + 8192);                                    \
    } while (0)

#define STGB(KH_, S_) do {                                                    \
        const char* g_ = B + ((size_t)((KH_) * 512 + rbB0) * 2048) + tid * 16;\
        char* l_ = Lc + (S_) * 24576 + 16384 + tid * 16;                      \
        gload_lds16(g_, l_);                                                  \
    } while (0)

// read frags of K-half HH_ into set SET_ (slot = HH_&3)
#define RDS(SET_, HH_) do {                                                   \
        const char* sl_ = Lc + ((HH_) & 3) * 24576;                           \
        _Pragma("unroll") for (int m_ = 0; m_ < 2; ++m_)                      \
        _Pragma("unroll") for (int ks_ = 0; ks_ < 2; ++ks_)                   \
            af[SET_][m_][ks_] = *(const bf16x8*)(sl_ + ((wr * 2 + m_) << 11)  \
                                           + (ks_ << 10) + (lane << 4));      \
        _Pragma("unroll") for (int n_ = 0; n_ < 2; ++n_)                      \
        _Pragma("unroll") for (int ks_ = 0; ks_ < 2; ++ks_)                   \
            bf[SET_][n_][ks_] = *(const bf16x8*)(sl_ + 16384                  \
                  + ((wc * 2 + n_) << 11) + (ks_ << 10) + (lane << 4));       \
    } while (0)

#define MM(SET_) do {                                                         \
        __builtin_amdgcn_s_setprio(1);                                        \
        _Pragma("unroll") for (int m_ = 0; m_ < 2; ++m_)                      \
        _Pragma("unroll") for (int n_ = 0; n_ < 2; ++n_)                      \
        _Pragma("unroll") for (int ks_ = 0; ks_ < 2; ++ks_)                   \
            acc[m_][n_] = __builtin_amdgcn_mfma_f32_32x32x16_bf16(            \
                af[SET_][m_][ks_], bf[SET_][n_][ks_], acc[m_][n_], 0, 0, 0);  \
        __builtin_amdgcn_s_setprio(0);                                        \
    } while (0)

    float rowacc = 0.f;
    #pragma unroll 1
    for (int ct = 0; ct < CT; ++ct) {
        const int rbB0 = (chunk * 16 + ct * 4); // 4 Rgroups of B (128 cols)
        f32x16 acc[2][2] = {};
        bf16x8 af[2][2][2], bf[2][2][2];        // [set][m|n][ks]

        // prologue: stage H0,H1,H2; wait H0,H1 landed (H2 in flight); read frags(0)
        STGA(0, 0); STGB(0, 0);
        STGA(1, 1); STGB(1, 1);
        STGA(2, 2); STGB(2, 2);
        asm volatile("s_waitcnt vmcnt(3)" ::: "memory");
        __builtin_amdgcn_s_barrier();
        RDS(0, 0);

        #pragma unroll
        for (int h = 0; h < NPH; ++h) {
            // reads for next phase drain under this phase's MFMA (compiler
            // emits lgkmcnt(8) before MFMA: waits set[h&1] only)
            if (h < NPH - 1) RDS((h + 1) & 1, h + 1);
            if (h < NPH - 3) { STGA(h + 3, (h + 3) & 3); STGB(h + 3, (h + 3) & 3); }
            MM(h & 1);
            // invariant: entering phase h+1, H(h+1),H(h+2) landed
            if (h < NPH - 3)       asm volatile("s_waitcnt vmcnt(3)" ::: "memory");
            else if (h == NPH - 3) asm volatile("s_waitcnt vmcnt(0)" ::: "memory");
            __builtin_amdgcn_s_barrier();
        }

        // epilogue: C/D 32x32: col=lane&31, row=(r&3)+8*(r>>2)+4*(lane>>5)
        #pragma unroll
        for (int m = 0; m < 2; ++m) {
            float rs[16];
            #pragma unroll
            for (int r = 0; r < 16; ++r)
                rs[r] = __builtin_amdgcn_exp2f(acc[m][0][r])
                      + __builtin_amdgcn_exp2f(acc[m][1][r]);
            #pragma unroll
            for (int off = 16; off >= 1; off >>= 1)
                #pragma unroll
                for (int r = 0; r < 16; ++r)
                    rs[r] += __shfl_xor(rs[r], off);
            if ((lane & 31) == 0) {
                const int rb = wr * 64 + m * 32 + (lane >> 5) * 4;
                #pragma unroll
                for (int r = 0; r < 16; ++r)
                    rowsum[wc][rb + (r & 3) + 8 * (r >> 2)] = rs[r];
            }
        }
        __syncthreads();
        if (tid < BM) rowacc += rowsum[0][tid] + rowsum[1][tid];
        __syncthreads();
    }
#undef STGA
#undef STGB
#undef RDS
#undef MM
    if (tid < BM) S_part[(size_t)chunk * NROWS + brow + tid] = rowacc;
}

// ---- kernel 3: diagonal logits (log2-scaled), fragment-major panel ----
__global__ void k_diag(const char* __restrict__ A, const char* __restrict__ B,
                       float* __restrict__ diag) {
    const int row  = blockIdx.x * 4 + (threadIdx.x >> 6);
    const int lane = threadIdx.x & 63;
    const int kh = lane >> 2, q = lane & 3;
    const size_t gr = ((size_t)(kh * 512 + (row >> 5)) * 2 + (q >> 1)) * 64
                    + ((q & 1) << 5) + (row & 31);
    const bf16x8 va = *(const bf16x8*)(A + gr * 16);
    const bf16x8 vb = *(const bf16x8*)(B + gr * 16);
    float d = 0.f;
    #pragma unroll
    for (int i = 0; i < 8; ++i) d += (float)va[i] * (float)vb[i];
    #pragma unroll
    for (int off2 = 1; off2 < 64; off2 <<= 1) d += __shfl_xor(d, off2);
    if (lane == 0) diag[row] = d;
}

// ---- kernel 4: per-row loss + deterministic block partials ----
__global__ void k_loss(const float* __restrict__ S_part, const float* __restrict__ diag,
                       float* __restrict__ partial) {
    const int g = blockIdx.x * 256 + threadIdx.x;
    float S = 0.f;
    #pragma unroll
    for (int c = 0; c < NCHUNK; ++c) S += S_part[(size_t)c * NROWS + g];
    float v = logf(S) - diag[g] * LN2;   // diag is log2-scaled
    __shared__ float wsum[4];
    #pragma unroll
    for (int off = 1; off < 64; off <<= 1) v += __shfl_xor(v, off);
    if ((threadIdx.x & 63) == 0) wsum[threadIdx.x >> 6] = v;
    __syncthreads();
    if (threadIdx.x == 0) partial[blockIdx.x] = wsum[0] + wsum[1] + wsum[2] + wsum[3];
}

__global__ void k_final(const float* __restrict__ partial, float* __restrict__ out) {
    float v = partial[threadIdx.x];
    #pragma unroll
    for (int off = 1; off < 64; off <<= 1) v += __shfl_xor(v, off);
    if (threadIdx.x == 0) out[0] = v * (1.0f / (float)NROWS);
}

extern "C" void kernel_launch(void* const* d_in, const int* in_sizes, int n_in,
                              void* d_out, int out_size, void* d_ws, size_t ws_size,
                              hipStream_t stream) {
    const float* f1 = (const float*)d_in[0];
    const float* f2 = (const float*)d_in[1];
    float* out = (float*)d_out;

    char* ws = (char*)d_ws;
    char*  f1p   = ws;                                  // 16 MB panel
    char*  f2p   = ws + (16u << 20);                    // 16 MB panel
    float* S_part = (float*)(ws + (32u << 20));         // 2 MB [NCHUNK][NROWS]
    float* diag   = (float*)(ws + (34u << 20));         // 64 KB
    float* part   = (float*)(ws + (34u << 20) + (1u << 16)); // 256 B

    k_norm<<<dim3(NROWS / 4), dim3(256), 0, stream>>>(f1, f1p, INV_T * LOG2E);
    k_norm<<<dim3(NROWS / 4), dim3(256), 0, stream>>>(f2, f2p, 1.0f);
    // 2048 blocks: 64 brow x 32 chunk (each block: 256 rows x 512 cols via CT=4)
    k_gemm<<<dim3((NROWS / BM) * NCHUNK), dim3(512), 0, stream>>>(f1p, f2p, S_part);
    k_diag<<<dim3(NROWS / 4), dim3(256), 0, stream>>>(f1p, f2p, diag);
    k_loss<<<dim3(NROWS / 256), dim3(256), 0, stream>>>(S_part, diag, part);
    k_final<<<dim3(1), dim3(64), 0, stream>>>(part, out);
}

// Round 11
// 350.203 us; speedup vs baseline: 1.3594x; 1.0234x over previous
//
#include <hip/hip_runtime.h>
#include <stdint.h>

#define NROWS 16384
#define KDIM  512
#define BM 128          // block rows
#define BN 256          // per-ct column strip
#define CT 2            // strips per block -> 512-col chunk
#define NCHUNK 32       // 16384 / 512
#define NPH 16          // K-halves of 32: 512/32
#define SLOT 24576      // A 8KB + B 16KB
#define INV_T 14.285714285714286f
#define LOG2E 1.4426950408889634f
#define LN2   0.6931471805599453f

typedef __bf16 bf16x8 __attribute__((ext_vector_type(8)));
typedef float  f32x16 __attribute__((ext_vector_type(16)));
typedef unsigned short u16x8 __attribute__((ext_vector_type(8)));

// async global->LDS, 16B/lane; LDS dest = wave-uniform base + lane*16
__device__ __forceinline__ void gload_lds16(const void* gptr, void* lptr) {
    uint32_t loff = (uint32_t)(uintptr_t)lptr;
    loff = __builtin_amdgcn_readfirstlane(loff);
    __builtin_amdgcn_global_load_lds(
        (const uint32_t __attribute__((address_space(1)))*)(uintptr_t)gptr,
        (uint32_t __attribute__((address_space(3)))*)(uintptr_t)loff,
        16, 0, 0);
}

// Fragment-major panel for mfma_32x32x16_bf16 (verified exact in R5/R9/R10):
// granule(row r, kh=k/32, q=(k/8)&3) at ((kh*512 + r/32)*2 + (q>>1))*64 + (q&1)*32 + (r&31)
// Wave frag read = Rgroup*2048 + ks*1024 + lane*16 : lane-contiguous, conflict-free.

// ---- kernel 1: L2 normalize + scale + bf16 cast into fragment-major panel ----
__global__ void k_norm(const float* __restrict__ X, char* __restrict__ Y, float scale) {
    const int row  = blockIdx.x * 4 + (threadIdx.x >> 6);
    const int lane = threadIdx.x & 63;
    const float* xr = X + (size_t)row * KDIM + lane * 8;
    float4 a = *(const float4*)xr;
    float4 b = *(const float4*)(xr + 4);
    float ss = a.x*a.x + a.y*a.y + a.z*a.z + a.w*a.w
             + b.x*b.x + b.y*b.y + b.z*b.z + b.w*b.w;
    #pragma unroll
    for (int off = 1; off < 64; off <<= 1) ss += __shfl_xor(ss, off);
    const float s = scale / fmaxf(sqrtf(ss), 1e-12f);
    __bf16 o[8];
    o[0] = (__bf16)(a.x * s); o[1] = (__bf16)(a.y * s);
    o[2] = (__bf16)(a.z * s); o[3] = (__bf16)(a.w * s);
    o[4] = (__bf16)(b.x * s); o[5] = (__bf16)(b.y * s);
    o[6] = (__bf16)(b.z * s); o[7] = (__bf16)(b.w * s);
    const int kh = lane >> 2, q = lane & 3;
    const size_t gr = ((size_t)(kh * 512 + (row >> 5)) * 2 + (q >> 1)) * 64
                    + ((q & 1) << 5) + (row & 31);
    *(u16x8*)(Y + gr * 16) = *(const u16x8*)o;
}

// ---- kernel 2: fused GEMM + exp2 + row-sum. 128x256 per step, 4 waves (2Mx2N),
// wave tile 64x128, 32x32x16 MFMA, ring-3 24KB slots, 2 blocks/CU.
__global__ __launch_bounds__(256, 2) void k_gemm(const char* __restrict__ A,
                                                 const char* __restrict__ B,
                                                 float* __restrict__ S_part) {
    __shared__ __align__(16) char L[3 * SLOT];    // 72KB -> 2 blocks/CU
    __shared__ float rowsum[2][BM];
    char* Lc = (char*)L;

    const int tid  = threadIdx.x;
    const int lane = tid & 63;
    const int w    = tid >> 6;           // 0..3
    const int wr   = w >> 1, wc = w & 1; // 2M x 2N; wave tile 64x128
    // XCD swizzle: 4096 blocks; per XCD 16 supertiles of (8 brow x 4 chunk)
    const int bid  = blockIdx.x;
    const int xcd  = bid & 7;
    const int idx  = bid >> 3;           // 0..511
    const int st   = idx >> 5;           // 0..15
    const int wsub = idx & 31;
    const int sg   = xcd * 16 + st;      // 0..127
    const int bg   = sg & 15, cg = sg >> 4;
    const int brow  = (bg * 8 + (wsub >> 2)) * BM;   // 0..127 * 128
    const int chunk = cg * 4 + (wsub & 3);           // 0..31, 512-col chunk
    const int rbA0 = brow >> 5;          // 4 Rgroups of A

#define STGA(KH_, S_) do {                                                    \
        const char* g_ = A + ((size_t)((KH_) * 512 + rbA0) * 2048) + tid * 16;\
        char* l_ = Lc + (S_) * SLOT + tid * 16;                               \
        gload_lds16(g_,        l_);                                           \
        gload_lds16(g_ + 4096, l_ + 4096);                                    \
    } while (0)

#define STGB(KH_, S_) do {                                                    \
        const char* g_ = B + ((size_t)((KH_) * 512 + rbB0) * 2048) + tid * 16;\
        char* l_ = Lc + (S_) * SLOT + 8192 + tid * 16;                        \
        gload_lds16(g_,         l_);                                          \
        gload_lds16(g_ +  4096, l_ +  4096);                                  \
        gload_lds16(g_ +  8192, l_ +  8192);                                  \
        gload_lds16(g_ + 12288, l_ + 12288);                                  \
    } while (0)

// read frags of K-half HH_ from slot (HH_%3)
#define RDS(HH_) do {                                                         \
        const char* sl_ = Lc + ((HH_) % 3) * SLOT;                            \
        _Pragma("unroll") for (int m_ = 0; m_ < 2; ++m_)                      \
        _Pragma("unroll") for (int ks_ = 0; ks_ < 2; ++ks_)                   \
            af[m_][ks_] = *(const bf16x8*)(sl_ + ((wr * 2 + m_) << 11)        \
                                           + (ks_ << 10) + (lane << 4));      \
        _Pragma("unroll") for (int n_ = 0; n_ < 4; ++n_)                      \
        _Pragma("unroll") for (int ks_ = 0; ks_ < 2; ++ks_)                   \
            bf[n_][ks_] = *(const bf16x8*)(sl_ + 8192                         \
                  + ((wc * 4 + n_) << 11) + (ks_ << 10) + (lane << 4));       \
    } while (0)

#define MM() do {                                                             \
        __builtin_amdgcn_s_setprio(1);                                        \
        _Pragma("unroll") for (int m_ = 0; m_ < 2; ++m_)                      \
        _Pragma("unroll") for (int n_ = 0; n_ < 4; ++n_)                      \
        _Pragma("unroll") for (int ks_ = 0; ks_ < 2; ++ks_)                   \
            acc[m_][n_] = __builtin_amdgcn_mfma_f32_32x32x16_bf16(            \
                af[m_][ks_], bf[n_][ks_], acc[m_][n_], 0, 0, 0);              \
        __builtin_amdgcn_s_setprio(0);                                        \
    } while (0)

    float rowacc = 0.f;
    #pragma unroll 1
    for (int ct = 0; ct < CT; ++ct) {
        const int rbB0 = chunk * 16 + ct * 8;   // 8 Rgroups of B (256 cols)
        f32x16 acc[2][4] = {};
        bf16x8 af[2][2], bf[4][2];

        // prologue: stage H0->slot0, H1->slot1 (6 loads each); wait H0
        STGA(0, 0); STGB(0, 0);
        STGA(1, 1); STGB(1, 1);
        asm volatile("s_waitcnt vmcnt(6)" ::: "memory");
        __builtin_amdgcn_s_barrier();

        #pragma unroll
        for (int h = 0; h < NPH; ++h) {
            RDS(h);
            if (h < NPH - 2) { STGA(h + 2, (h + 2) % 3); STGB(h + 2, (h + 2) % 3); }
            MM();
            // invariant: entering phase h+1, H(h+1) landed (its 6 loads drained)
            if (h < NPH - 2)       asm volatile("s_waitcnt vmcnt(6)" ::: "memory");
            else if (h == NPH - 2) asm volatile("s_waitcnt vmcnt(0)" ::: "memory");
            __builtin_amdgcn_s_barrier();
        }

        // epilogue: C/D 32x32: col=lane&31, row=(r&3)+8*(r>>2)+4*(lane>>5)
        #pragma unroll
        for (int m = 0; m < 2; ++m) {
            float rs[16];
            #pragma unroll
            for (int r = 0; r < 16; ++r)
                rs[r] = __builtin_amdgcn_exp2f(acc[m][0][r])
                      + __builtin_amdgcn_exp2f(acc[m][1][r])
                      + __builtin_amdgcn_exp2f(acc[m][2][r])
                      + __builtin_amdgcn_exp2f(acc[m][3][r]);
            #pragma unroll
            for (int off = 16; off >= 1; off >>= 1)
                #pragma unroll
                for (int r = 0; r < 16; ++r)
                    rs[r] += __shfl_xor(rs[r], off);
            if ((lane & 31) == 0) {
                const int rb = wr * 64 + m * 32 + (lane >> 5) * 4;
                #pragma unroll
                for (int r = 0; r < 16; ++r)
                    rowsum[wc][rb + (r & 3) + 8 * (r >> 2)] = rs[r];
            }
        }
        __syncthreads();
        if (tid < BM) rowacc += rowsum[0][tid] + rowsum[1][tid];
        __syncthreads();
    }
#undef STGA
#undef STGB
#undef RDS
#undef MM
    if (tid < BM) S_part[(size_t)chunk * NROWS + brow + tid] = rowacc;
}

// ---- kernel 3: diagonal logits (log2-scaled), fragment-major panel ----
__global__ void k_diag(const char* __restrict__ A, const char* __restrict__ B,
                       float* __restrict__ diag) {
    const int row  = blockIdx.x * 4 + (threadIdx.x >> 6);
    const int lane = threadIdx.x & 63;
    const int kh = lane >> 2, q = lane & 3;
    const size_t gr = ((size_t)(kh * 512 + (row >> 5)) * 2 + (q >> 1)) * 64
                    + ((q & 1) << 5) + (row & 31);
    const bf16x8 va = *(const bf16x8*)(A + gr * 16);
    const bf16x8 vb = *(const bf16x8*)(B + gr * 16);
    float d = 0.f;
    #pragma unroll
    for (int i = 0; i < 8; ++i) d += (float)va[i] * (float)vb[i];
    #pragma unroll
    for (int off2 = 1; off2 < 64; off2 <<= 1) d += __shfl_xor(d, off2);
    if (lane == 0) diag[row] = d;
}

// ---- kernel 4: per-row loss + deterministic block partials ----
__global__ void k_loss(const float* __restrict__ S_part, const float* __restrict__ diag,
                       float* __restrict__ partial) {
    const int g = blockIdx.x * 256 + threadIdx.x;
    float S = 0.f;
    #pragma unroll
    for (int c = 0; c < NCHUNK; ++c) S += S_part[(size_t)c * NROWS + g];
    float v = logf(S) - diag[g] * LN2;   // diag is log2-scaled
    __shared__ float wsum[4];
    #pragma unroll
    for (int off = 1; off < 64; off <<= 1) v += __shfl_xor(v, off);
    if ((threadIdx.x & 63) == 0) wsum[threadIdx.x >> 6] = v;
    __syncthreads();
    if (threadIdx.x == 0) partial[blockIdx.x] = wsum[0] + wsum[1] + wsum[2] + wsum[3];
}

__global__ void k_final(const float* __restrict__ partial, float* __restrict__ out) {
    float v = partial[threadIdx.x];
    #pragma unroll
    for (int off = 1; off < 64; off <<= 1) v += __shfl_xor(v, off);
    if (threadIdx.x == 0) out[0] = v * (1.0f / (float)NROWS);
}

extern "C" void kernel_launch(void* const* d_in, const int* in_sizes, int n_in,
                              void* d_out, int out_size, void* d_ws, size_t ws_size,
                              hipStream_t stream) {
    const float* f1 = (const float*)d_in[0];
    const float* f2 = (const float*)d_in[1];
    float* out = (float*)d_out;

    char* ws = (char*)d_ws;
    char*  f1p   = ws;                                  // 16 MB panel
    char*  f2p   = ws + (16u << 20);                    // 16 MB panel
    float* S_part = (float*)(ws + (32u << 20));         // 2 MB [NCHUNK][NROWS]
    float* diag   = (float*)(ws + (34u << 20));         // 64 KB
    float* part   = (float*)(ws + (34u << 20) + (1u << 16)); // 256 B

    k_norm<<<dim3(NROWS / 4), dim3(256), 0, stream>>>(f1, f1p, INV_T * LOG2E);
    k_norm<<<dim3(NROWS / 4), dim3(256), 0, stream>>>(f2, f2p, 1.0f);
    // 4096 blocks: 128 brow x 32 chunk (each block: 128 rows x 512 cols via CT=2)
    k_gemm<<<dim3((NROWS / BM) * NCHUNK), dim3(256), 0, stream>>>(f1p, f2p, S_part);
    k_diag<<<dim3(NROWS / 4), dim3(256), 0, stream>>>(f1p, f2p, diag);
    k_loss<<<dim3(NROWS / 256), dim3(256), 0, stream>>>(S_part, diag, part);
    k_final<<<dim3(1), dim3(64), 0, stream>>>(part, out);
}

// Round 12
// 341.668 us; speedup vs baseline: 1.3933x; 1.0250x over previous
//
#include <hip/hip_runtime.h>
#include <stdint.h>

#define NROWS 16384
#define KDIM  512
#define BM 128          // block rows
#define BN 256          // per-ct column strip
#define CT 2            // strips per block -> 512-col chunk
#define NCHUNK 32       // 16384 / 512
#define NPH 16          // K-halves of 32: 512/32
#define SLOT 24576      // A 8KB + B 16KB
#define INV_T 14.285714285714286f
#define LOG2E 1.4426950408889634f
#define LN2   0.6931471805599453f

typedef __bf16 bf16x8 __attribute__((ext_vector_type(8)));
typedef float  f32x16 __attribute__((ext_vector_type(16)));
typedef unsigned short u16x8 __attribute__((ext_vector_type(8)));

// async global->LDS, 16B/lane; LDS dest = wave-uniform base + lane*16
__device__ __forceinline__ void gload_lds16(const void* gptr, void* lptr) {
    uint32_t loff = (uint32_t)(uintptr_t)lptr;
    loff = __builtin_amdgcn_readfirstlane(loff);
    __builtin_amdgcn_global_load_lds(
        (const uint32_t __attribute__((address_space(1)))*)(uintptr_t)gptr,
        (uint32_t __attribute__((address_space(3)))*)(uintptr_t)loff,
        16, 0, 0);
}

// Fragment-major panel for mfma_32x32x16_bf16 (verified exact in R5/R9/R10/R11):
// granule(row r, kh=k/32, q=(k/8)&3) at ((kh*512 + r/32)*2 + (q>>1))*64 + (q&1)*32 + (r&31)
// Wave frag read = Rgroup*2048 + ks*1024 + lane*16 : lane-contiguous, conflict-free.

// ---- kernel 1: L2 normalize + scale + bf16 cast into fragment-major panel ----
__global__ void k_norm(const float* __restrict__ X, char* __restrict__ Y, float scale) {
    const int row  = blockIdx.x * 4 + (threadIdx.x >> 6);
    const int lane = threadIdx.x & 63;
    const float* xr = X + (size_t)row * KDIM + lane * 8;
    float4 a = *(const float4*)xr;
    float4 b = *(const float4*)(xr + 4);
    float ss = a.x*a.x + a.y*a.y + a.z*a.z + a.w*a.w
             + b.x*b.x + b.y*b.y + b.z*b.z + b.w*b.w;
    #pragma unroll
    for (int off = 1; off < 64; off <<= 1) ss += __shfl_xor(ss, off);
    const float s = scale / fmaxf(sqrtf(ss), 1e-12f);
    __bf16 o[8];
    o[0] = (__bf16)(a.x * s); o[1] = (__bf16)(a.y * s);
    o[2] = (__bf16)(a.z * s); o[3] = (__bf16)(a.w * s);
    o[4] = (__bf16)(b.x * s); o[5] = (__bf16)(b.y * s);
    o[6] = (__bf16)(b.z * s); o[7] = (__bf16)(b.w * s);
    const int kh = lane >> 2, q = lane & 3;
    const size_t gr = ((size_t)(kh * 512 + (row >> 5)) * 2 + (q >> 1)) * 64
                    + ((q & 1) << 5) + (row & 31);
    *(u16x8*)(Y + gr * 16) = *(const u16x8*)o;
}

// ---- kernel 2: fused GEMM + exp2 + row-sum. 128x256 per step, 4 waves (2Mx2N),
// wave tile 64x128, 32x32x16 MFMA, ring-3 24KB slots, 2 blocks/CU (LDS-limited).
// launch_bounds(256,1): lift VGPR clamp to let acc[2][4]+frags live in registers.
__global__ __launch_bounds__(256, 1) void k_gemm(const char* __restrict__ A,
                                                 const char* __restrict__ B,
                                                 float* __restrict__ S_part) {
    __shared__ __align__(16) char L[3 * SLOT];    // 72KB -> 2 blocks/CU
    __shared__ float rowsum[2][BM];
    char* Lc = (char*)L;

    const int tid  = threadIdx.x;
    const int lane = tid & 63;
    const int w    = tid >> 6;           // 0..3
    const int wr   = w >> 1, wc = w & 1; // 2M x 2N; wave tile 64x128
    // XCD swizzle: 4096 blocks; per XCD 16 supertiles of (8 brow x 4 chunk)
    const int bid  = blockIdx.x;
    const int xcd  = bid & 7;
    const int idx  = bid >> 3;           // 0..511
    const int st   = idx >> 5;           // 0..15
    const int wsub = idx & 31;
    const int sg   = xcd * 16 + st;      // 0..127
    const int bg   = sg & 15, cg = sg >> 4;
    const int brow  = (bg * 8 + (wsub >> 2)) * BM;   // 0..127 * 128
    const int chunk = cg * 4 + (wsub & 3);           // 0..31, 512-col chunk
    const int rbA0 = brow >> 5;          // 4 Rgroups of A

#define STGA(KH_, S_) do {                                                    \
        const char* g_ = A + ((size_t)((KH_) * 512 + rbA0) * 2048) + tid * 16;\
        char* l_ = Lc + (S_) * SLOT + tid * 16;                               \
        gload_lds16(g_,        l_);                                           \
        gload_lds16(g_ + 4096, l_ + 4096);                                    \
    } while (0)

#define STGB(KH_, S_) do {                                                    \
        const char* g_ = B + ((size_t)((KH_) * 512 + rbB0) * 2048) + tid * 16;\
        char* l_ = Lc + (S_) * SLOT + 8192 + tid * 16;                        \
        gload_lds16(g_,         l_);                                          \
        gload_lds16(g_ +  4096, l_ +  4096);                                  \
        gload_lds16(g_ +  8192, l_ +  8192);                                  \
        gload_lds16(g_ + 12288, l_ + 12288);                                  \
    } while (0)

// read frags of K-half HH_ from slot (HH_%3)
#define RDS(HH_) do {                                                         \
        const char* sl_ = Lc + ((HH_) % 3) * SLOT;                            \
        _Pragma("unroll") for (int m_ = 0; m_ < 2; ++m_)                      \
        _Pragma("unroll") for (int ks_ = 0; ks_ < 2; ++ks_)                   \
            af[m_][ks_] = *(const bf16x8*)(sl_ + ((wr * 2 + m_) << 11)        \
                                           + (ks_ << 10) + (lane << 4));      \
        _Pragma("unroll") for (int n_ = 0; n_ < 4; ++n_)                      \
        _Pragma("unroll") for (int ks_ = 0; ks_ < 2; ++ks_)                   \
            bf[n_][ks_] = *(const bf16x8*)(sl_ + 8192                         \
                  + ((wc * 4 + n_) << 11) + (ks_ << 10) + (lane << 4));       \
    } while (0)

#define MM() do {                                                             \
        __builtin_amdgcn_s_setprio(1);                                        \
        _Pragma("unroll") for (int m_ = 0; m_ < 2; ++m_)                      \
        _Pragma("unroll") for (int n_ = 0; n_ < 4; ++n_)                      \
        _Pragma("unroll") for (int ks_ = 0; ks_ < 2; ++ks_)                   \
            acc[m_][n_] = __builtin_amdgcn_mfma_f32_32x32x16_bf16(            \
                af[m_][ks_], bf[n_][ks_], acc[m_][n_], 0, 0, 0);              \
        __builtin_amdgcn_s_setprio(0);                                        \
    } while (0)

    float rowacc = 0.f;
    #pragma unroll 1
    for (int ct = 0; ct < CT; ++ct) {
        const int rbB0 = chunk * 16 + ct * 8;   // 8 Rgroups of B (256 cols)
        f32x16 acc[2][4] = {};
        bf16x8 af[2][2], bf[4][2];

        // prologue: stage H0->slot0, H1->slot1 (6 loads each); wait H0
        STGA(0, 0); STGB(0, 0);
        STGA(1, 1); STGB(1, 1);
        asm volatile("s_waitcnt vmcnt(6)" ::: "memory");
        __builtin_amdgcn_s_barrier();

        #pragma unroll
        for (int h = 0; h < NPH; ++h) {
            RDS(h);
            if (h < NPH - 2) { STGA(h + 2, (h + 2) % 3); STGB(h + 2, (h + 2) % 3); }
            MM();
            // invariant: entering phase h+1, H(h+1) landed (its 6 loads drained)
            if (h < NPH - 2)       asm volatile("s_waitcnt vmcnt(6)" ::: "memory");
            else if (h == NPH - 2) asm volatile("s_waitcnt vmcnt(0)" ::: "memory");
            __builtin_amdgcn_s_barrier();
        }

        // epilogue: C/D 32x32: col=lane&31, row=(r&3)+8*(r>>2)+4*(lane>>5)
        #pragma unroll
        for (int m = 0; m < 2; ++m) {
            float rs[16];
            #pragma unroll
            for (int r = 0; r < 16; ++r)
                rs[r] = __builtin_amdgcn_exp2f(acc[m][0][r])
                      + __builtin_amdgcn_exp2f(acc[m][1][r])
                      + __builtin_amdgcn_exp2f(acc[m][2][r])
                      + __builtin_amdgcn_exp2f(acc[m][3][r]);
            #pragma unroll
            for (int off = 16; off >= 1; off >>= 1)
                #pragma unroll
                for (int r = 0; r < 16; ++r)
                    rs[r] += __shfl_xor(rs[r], off);
            if ((lane & 31) == 0) {
                const int rb = wr * 64 + m * 32 + (lane >> 5) * 4;
                #pragma unroll
                for (int r = 0; r < 16; ++r)
                    rowsum[wc][rb + (r & 3) + 8 * (r >> 2)] = rs[r];
            }
        }
        __syncthreads();
        if (tid < BM) rowacc += rowsum[0][tid] + rowsum[1][tid];
        __syncthreads();
    }
#undef STGA
#undef STGB
#undef RDS
#undef MM
    if (tid < BM) S_part[(size_t)chunk * NROWS + brow + tid] = rowacc;
}

// ---- kernel 3: diagonal logits (log2-scaled), fragment-major panel ----
__global__ void k_diag(const char* __restrict__ A, const char* __restrict__ B,
                       float* __restrict__ diag) {
    const int row  = blockIdx.x * 4 + (threadIdx.x >> 6);
    const int lane = threadIdx.x & 63;
    const int kh = lane >> 2, q = lane & 3;
    const size_t gr = ((size_t)(kh * 512 + (row >> 5)) * 2 + (q >> 1)) * 64
                    + ((q & 1) << 5) + (row & 31);
    const bf16x8 va = *(const bf16x8*)(A + gr * 16);
    const bf16x8 vb = *(const bf16x8*)(B + gr * 16);
    float d = 0.f;
    #pragma unroll
    for (int i = 0; i < 8; ++i) d += (float)va[i] * (float)vb[i];
    #pragma unroll
    for (int off2 = 1; off2 < 64; off2 <<= 1) d += __shfl_xor(d, off2);
    if (lane == 0) diag[row] = d;
}

// ---- kernel 4: per-row loss + deterministic block partials ----
__global__ void k_loss(const float* __restrict__ S_part, const float* __restrict__ diag,
                       float* __restrict__ partial) {
    const int g = blockIdx.x * 256 + threadIdx.x;
    float S = 0.f;
    #pragma unroll
    for (int c = 0; c < NCHUNK; ++c) S += S_part[(size_t)c * NROWS + g];
    float v = logf(S) - diag[g] * LN2;   // diag is log2-scaled
    __shared__ float wsum[4];
    #pragma unroll
    for (int off = 1; off < 64; off <<= 1) v += __shfl_xor(v, off);
    if ((threadIdx.x & 63) == 0) wsum[threadIdx.x >> 6] = v;
    __syncthreads();
    if (threadIdx.x == 0) partial[blockIdx.x] = wsum[0] + wsum[1] + wsum[2] + wsum[3];
}

__global__ void k_final(const float* __restrict__ partial, float* __restrict__ out) {
    float v = partial[threadIdx.x];
    #pragma unroll
    for (int off = 1; off < 64; off <<= 1) v += __shfl_xor(v, off);
    if (threadIdx.x == 0) out[0] = v * (1.0f / (float)NROWS);
}

extern "C" void kernel_launch(void* const* d_in, const int* in_sizes, int n_in,
                              void* d_out, int out_size, void* d_ws, size_t ws_size,
                              hipStream_t stream) {
    const float* f1 = (const float*)d_in[0];
    const float* f2 = (const float*)d_in[1];
    float* out = (float*)d_out;

    char* ws = (char*)d_ws;
    char*  f1p   = ws;                                  // 16 MB panel
    char*  f2p   = ws + (16u << 20);                    // 16 MB panel
    float* S_part = (float*)(ws + (32u << 20));         // 2 MB [NCHUNK][NROWS]
    float* diag   = (float*)(ws + (34u << 20));         // 64 KB
    float* part   = (float*)(ws + (34u << 20) + (1u << 16)); // 256 B

    k_norm<<<dim3(NROWS / 4), dim3(256), 0, stream>>>(f1, f1p, INV_T * LOG2E);
    k_norm<<<dim3(NROWS / 4), dim3(256), 0, stream>>>(f2, f2p, 1.0f);
    // 4096 blocks: 128 brow x 32 chunk (each block: 128 rows x 512 cols via CT=2)
    k_gemm<<<dim3((NROWS / BM) * NCHUNK), dim3(256), 0, stream>>>(f1p, f2p, S_part);
    k_diag<<<dim3(NROWS / 4), dim3(256), 0, stream>>>(f1p, f2p, diag);
    k_loss<<<dim3(NROWS / 256), dim3(256), 0, stream>>>(S_part, diag, part);
    k_final<<<dim3(1), dim3(64), 0, stream>>>(part, out);
}